// Round 4
// baseline (1050.071 us; speedup 1.0000x reference)
//
#include <hip/hip_runtime.h>

#define NSH 512    // NUM_SHARDS
#define NC  256    // NUM_CLUSTERS
#define NI  1024   // INPUT_SIZE
#define NO  1024   // OUTPUT_SIZE
#define NB  1024   // BATCH
#define NMAX 8     // samples per pass per shard-block
#define IC  8      // i-chunks for logit kernel   (chunk = 128 rows)
#define OC  8      // o-chunks for combine kernel (chunk = 128 cols)
#define UF  8      // float4 loads in flight per thread

// ---------------- Kernel 1: group samples by shard + zero done[] ------------
__global__ __launch_bounds__(512) void group_kernel(const int* __restrict__ shard,
                                                    int* __restrict__ order,
                                                    int* __restrict__ base,
                                                    int* __restrict__ cnt,
                                                    int* __restrict__ done) {
    __shared__ int h[NSH];
    __shared__ int woff[8];
    __shared__ int cur[NSH];
    const int tid  = threadIdx.x;      // 512 threads == NSH
    const int lane = tid & 63;
    const int w8   = tid >> 6;
    h[tid] = 0;
    done[tid] = 0;
    __syncthreads();
    for (int i = tid; i < NB; i += 512) atomicAdd(&h[shard[i]], 1);
    __syncthreads();
    const int v = h[tid];
    int inc = v;                        // inclusive scan within wave
    #pragma unroll
    for (int off = 1; off < 64; off <<= 1) {
        int t = __shfl_up(inc, off, 64);
        if (lane >= off) inc += t;
    }
    if (lane == 63) woff[w8] = inc;
    __syncthreads();
    if (tid == 0) {
        int a = 0;
        #pragma unroll
        for (int i = 0; i < 8; ++i) { int t = woff[i]; woff[i] = a; a += t; }
    }
    __syncthreads();
    const int b0 = woff[w8] + inc - v;  // exclusive prefix
    base[tid] = b0;
    cnt[tid]  = v;
    cur[tid]  = b0;
    __syncthreads();
    for (int i = tid; i < NB; i += 512) {
        int pos = atomicAdd(&cur[shard[i]], 1);
        order[pos] = i;
    }
}

// ---------------- Kernel 2: partial logits + fused softmax ------------------
// block (s, ic): partial[ic][b][c] = sum_{i in chunk} key[b][i] * W[s][i][c]
// last block per shard: logits = sum partials + bias -> softmax -> outq
__global__ __launch_bounds__(256) void logit_kernel(
        const int*   __restrict__ order,
        const int*   __restrict__ base,
        const int*   __restrict__ cnt,
        const float* __restrict__ key,
        const float* __restrict__ wgt,
        const float* __restrict__ bias,
        float*       __restrict__ partial,
        float*       __restrict__ outq,
        int*         __restrict__ done) {
    const int s  = blockIdx.x >> 3;
    const int ic = blockIdx.x & 7;
    const int n_tot = cnt[s];
    if (n_tot == 0) return;
    const int b0   = base[s];
    const int tid  = threadIdx.x;
    const int w    = tid >> 6;            // i-phase (wave)
    const int lane = tid & 63;
    const int c4   = lane << 2;           // 4 clusters per lane

    const float* __restrict__ Wp =
        wgt + (size_t)s * (NI * NC) + (size_t)(ic * (NI / IC)) * NC;

    __shared__ float key_s[NMAX][NI / IC];  // [8][128] 4 KB
    __shared__ float red_s[4][2][NC];       // 8 KB
    __shared__ float xw[4];
    __shared__ int   samp_s[NMAX];
    __shared__ int   is_last;

    for (int p0 = 0; p0 < n_tot; p0 += NMAX) {
        const int n = min(NMAX, n_tot - p0);
        __syncthreads();
        if (tid < n) samp_s[tid] = order[b0 + p0 + tid];
        __syncthreads();

        {   // stage key chunk: 8 samples x 128 floats = 256 float4 (1/thread)
            const int ns = tid >> 5, e4 = tid & 31;
            float4 vv = make_float4(0.f, 0.f, 0.f, 0.f);
            if (ns < n)
                vv = *(const float4*)(key + (size_t)samp_s[ns] * NI
                                          + ic * (NI / IC) + (e4 << 2));
            *(float4*)&key_s[ns][e4 << 2] = vv;
        }
        __syncthreads();

        float4 acc[NMAX];
        #pragma unroll
        for (int j = 0; j < NMAX; ++j) acc[j] = make_float4(0.f, 0.f, 0.f, 0.f);

        #pragma unroll
        for (int k0 = 0; k0 < (NI / IC / 4); k0 += UF) {   // 4 iters
            float4 wv[UF];
            #pragma unroll
            for (int u = 0; u < UF; ++u)
                wv[u] = *(const float4*)(Wp + (size_t)(w + 4 * (k0 + u)) * NC + c4);
            #pragma unroll
            for (int u = 0; u < UF; ++u) {
                const int il = w + 4 * (k0 + u);
                #pragma unroll
                for (int j = 0; j < NMAX; ++j) {
                    const float k = key_s[j][il];
                    acc[j].x = fmaf(k, wv[u].x, acc[j].x);
                    acc[j].y = fmaf(k, wv[u].y, acc[j].y);
                    acc[j].z = fmaf(k, wv[u].z, acc[j].z);
                    acc[j].w = fmaf(k, wv[u].w, acc[j].w);
                }
            }
        }

        #pragma unroll
        for (int r = 0; r < 4; ++r) {       // cross-wave reduce, 2 samples/round
            __syncthreads();
            *(float4*)&red_s[w][0][c4] = acc[2 * r];
            *(float4*)&red_s[w][1][c4] = acc[2 * r + 1];
            __syncthreads();
            const float s0 = red_s[0][0][tid] + red_s[1][0][tid]
                           + red_s[2][0][tid] + red_s[3][0][tid];
            const float s1 = red_s[0][1][tid] + red_s[1][1][tid]
                           + red_s[2][1][tid] + red_s[3][1][tid];
            if (2 * r < n)
                partial[((size_t)ic * NB + samp_s[2 * r]) * NC + tid] = s0;
            if (2 * r + 1 < n)
                partial[((size_t)ic * NB + samp_s[2 * r + 1]) * NC + tid] = s1;
        }
    }

    // ---- completion count; last block of this shard does the softmax ----
    __threadfence();                        // release partial stores
    __syncthreads();
    if (tid == 0) is_last = (atomicAdd(&done[s], 1) == IC - 1);
    __syncthreads();
    if (!is_last) return;
    __threadfence();                        // acquire other blocks' partials

    const float bsc = bias[(size_t)s * NC + tid];
    for (int q = 0; q < n_tot; ++q) {
        const int b = order[b0 + q];
        float lg = bsc;
        #pragma unroll
        for (int ic2 = 0; ic2 < IC; ++ic2)
            lg += partial[((size_t)ic2 * NB + b) * NC + tid];
        float m = lg;
        #pragma unroll
        for (int off = 32; off >= 1; off >>= 1)
            m = fmaxf(m, __shfl_xor(m, off, 64));
        if (lane == 0) xw[w] = m;
        __syncthreads();
        m = fmaxf(fmaxf(xw[0], xw[1]), fmaxf(xw[2], xw[3]));
        const float e = __expf(lg - m);
        float sm = e;
        #pragma unroll
        for (int off = 32; off >= 1; off >>= 1)
            sm += __shfl_xor(sm, off, 64);
        __syncthreads();
        if (lane == 0) xw[w] = sm;
        __syncthreads();
        sm = xw[0] + xw[1] + xw[2] + xw[3];
        outq[(size_t)b * NC + tid] = e / sm;
        __syncthreads();                    // xw safe for next q
    }
}

// ---------------- Kernel 3: combine, block (s, oc), 8 half-wave c-phases ----
// lat_h[b][oc*128 + o] = sum_c prob[b][c] * L[s][c][oc*128 + o]
__global__ __launch_bounds__(256) void combine_kernel(
        const int*   __restrict__ order,
        const int*   __restrict__ base,
        const int*   __restrict__ cnt,
        const float* __restrict__ prob,
        const float* __restrict__ lat,
        float*       __restrict__ outp) {
    const int s  = blockIdx.x >> 3;
    const int oc = blockIdx.x & 7;
    const int n_tot = cnt[s];
    if (n_tot == 0) return;
    const int b0  = base[s];
    const int tid = threadIdx.x;
    const int hw  = tid >> 5;             // half-wave = c-phase 0..7
    const int o4  = (tid & 31) << 2;      // 4 outputs per lane within 128-chunk

    const float* __restrict__ Lp = lat + (size_t)s * (NC * NO) + oc * (NO / OC);

    __shared__ float prob_s[NMAX][NC];         // 8 KB
    __shared__ float red_s[8][2][NO / OC];     // [8][2][128] 8 KB
    __shared__ int   samp_s[NMAX];

    for (int p0 = 0; p0 < n_tot; p0 += NMAX) {
        const int n = min(NMAX, n_tot - p0);
        __syncthreads();
        if (tid < n) samp_s[tid] = order[b0 + p0 + tid];
        __syncthreads();

        // stage prob: 8 samples x 256 floats = 512 float4 (2/thread)
        for (int idx = tid; idx < NMAX * 64; idx += 256) {
            const int ns = idx >> 6;
            const int e4 = idx & 63;
            float4 v = make_float4(0.f, 0.f, 0.f, 0.f);
            if (ns < n)
                v = *(const float4*)(prob + (size_t)samp_s[ns] * NC + (e4 << 2));
            *(float4*)&prob_s[ns][e4 << 2] = v;
        }
        __syncthreads();

        float4 acc[NMAX];
        #pragma unroll
        for (int j = 0; j < NMAX; ++j) acc[j] = make_float4(0.f, 0.f, 0.f, 0.f);

        #pragma unroll
        for (int k0 = 0; k0 < 32; k0 += UF) {     // c = hw + 8*(k0+u)
            float4 lv[UF];
            #pragma unroll
            for (int u = 0; u < UF; ++u)
                lv[u] = *(const float4*)(Lp + (size_t)(hw + 8 * (k0 + u)) * NO + o4);
            #pragma unroll
            for (int u = 0; u < UF; ++u) {
                const int c = hw + 8 * (k0 + u);
                #pragma unroll
                for (int j = 0; j < NMAX; ++j) {
                    const float p = prob_s[j][c];
                    acc[j].x = fmaf(p, lv[u].x, acc[j].x);
                    acc[j].y = fmaf(p, lv[u].y, acc[j].y);
                    acc[j].z = fmaf(p, lv[u].z, acc[j].z);
                    acc[j].w = fmaf(p, lv[u].w, acc[j].w);
                }
            }
        }

        // cross-phase reduce (8 phases), 2 samples per round
        #pragma unroll
        for (int r = 0; r < 4; ++r) {
            __syncthreads();
            *(float4*)&red_s[hw][0][o4] = acc[2 * r];
            *(float4*)&red_s[hw][1][o4] = acc[2 * r + 1];
            __syncthreads();
            const int sel = tid >> 7;            // 0/1 -> which sample
            const int o   = tid & 127;
            float sum = red_s[0][sel][o] + red_s[1][sel][o]
                      + red_s[2][sel][o] + red_s[3][sel][o]
                      + red_s[4][sel][o] + red_s[5][sel][o]
                      + red_s[6][sel][o] + red_s[7][sel][o];
            const int j = 2 * r + sel;
            if (j < n)
                outp[(size_t)samp_s[j] * NO + oc * (NO / OC) + o] = sum;
        }
    }
}

// ---------------- launch ----------------------------------------------------
extern "C" void kernel_launch(void* const* d_in, const int* in_sizes, int n_in,
                              void* d_out, int out_size, void* d_ws, size_t ws_size,
                              hipStream_t stream) {
    const int*   shard = (const int*)  d_in[0];
    const float* key   = (const float*)d_in[1];
    const float* lat   = (const float*)d_in[2];
    const float* wgt   = (const float*)d_in[3];
    const float* bias  = (const float*)d_in[4];

    float* outp = (float*)d_out;                       // lat_h [NB][NO]
    float* outq = (float*)d_out + (size_t)NB * NO;     // prob  [NB][NC]

    int*   order   = (int*)d_ws;            // [NB]
    int*   base    = order + NB;            // [NSH]
    int*   cnt     = base + NSH;            // [NSH]
    int*   done    = cnt + NSH;             // [NSH]
    float* partial = (float*)(done + NSH);  // [IC][NB][NC] = 8 MB

    group_kernel  <<<1,        512, 0, stream>>>(shard, order, base, cnt, done);
    logit_kernel  <<<NSH * IC, 256, 0, stream>>>(order, base, cnt, key, wgt,
                                                 bias, partial, outq, done);
    combine_kernel<<<NSH * OC, 256, 0, stream>>>(order, base, cnt, outq, lat, outp);
}

// Round 5
// 297.675 us; speedup vs baseline: 3.5276x; 3.5276x over previous
//
#include <hip/hip_runtime.h>

#define NSH 512    // NUM_SHARDS
#define NC  256    // NUM_CLUSTERS
#define NI  1024   // INPUT_SIZE
#define NO  1024   // OUTPUT_SIZE
#define NB  1024   // BATCH
#define NMAX 8     // samples per pass per shard-block
#define IC  8      // i-chunks for logit kernel   (chunk = 128 rows)
#define OC  8      // o-chunks for combine kernel (chunk = 128 cols)
#define UF  8      // float4 loads in flight per thread

// ---------------- Kernel 1: group samples by shard (counting sort) ----------
__global__ __launch_bounds__(512) void group_kernel(const int* __restrict__ shard,
                                                    int* __restrict__ order,
                                                    int* __restrict__ base,
                                                    int* __restrict__ cnt) {
    __shared__ int h[NSH];
    __shared__ int woff[8];
    __shared__ int cur[NSH];
    const int tid  = threadIdx.x;      // 512 threads == NSH
    const int lane = tid & 63;
    const int w8   = tid >> 6;
    h[tid] = 0;
    __syncthreads();
    for (int i = tid; i < NB; i += 512) atomicAdd(&h[shard[i]], 1);
    __syncthreads();
    const int v = h[tid];
    int inc = v;                        // inclusive scan within wave
    #pragma unroll
    for (int off = 1; off < 64; off <<= 1) {
        int t = __shfl_up(inc, off, 64);
        if (lane >= off) inc += t;
    }
    if (lane == 63) woff[w8] = inc;
    __syncthreads();
    if (tid == 0) {
        int a = 0;
        #pragma unroll
        for (int i = 0; i < 8; ++i) { int t = woff[i]; woff[i] = a; a += t; }
    }
    __syncthreads();
    const int b0 = woff[w8] + inc - v;  // exclusive prefix
    base[tid] = b0;
    cnt[tid]  = v;
    cur[tid]  = b0;
    __syncthreads();
    for (int i = tid; i < NB; i += 512) {
        int pos = atomicAdd(&cur[shard[i]], 1);
        order[pos] = i;
    }
}

// ---------------- Kernel 2: partial logits, block (shard, i-chunk) ----------
// partial[ic][b][c] = sum_{i in chunk} key[b][i] * W[s][i][c]
__global__ __launch_bounds__(256) void logit_kernel(
        const int*   __restrict__ order,
        const int*   __restrict__ base,
        const int*   __restrict__ cnt,
        const float* __restrict__ key,
        const float* __restrict__ wgt,
        float*       __restrict__ partial) {
    const int s  = blockIdx.x >> 3;
    const int ic = blockIdx.x & 7;
    const int n_tot = cnt[s];
    if (n_tot == 0) return;
    const int b0  = base[s];
    const int tid = threadIdx.x;
    const int w   = tid >> 6;            // i-phase (wave)
    const int c4  = (tid & 63) << 2;     // 4 clusters per lane

    const float* __restrict__ Wp =
        wgt + (size_t)s * (NI * NC) + (size_t)(ic * (NI / IC)) * NC;

    __shared__ float key_s[NMAX][NI / IC];  // [8][128]  4 KB
    __shared__ float red_s[4][2][NC];       //           8 KB
    __shared__ int   samp_s[NMAX];

    for (int p0 = 0; p0 < n_tot; p0 += NMAX) {
        const int n = min(NMAX, n_tot - p0);
        __syncthreads();
        if (tid < n) samp_s[tid] = order[b0 + p0 + tid];
        __syncthreads();

        {   // stage key chunk: 8 samples x 128 floats = 256 float4 (1/thread)
            const int ns = tid >> 5, e4 = tid & 31;
            float4 vv = make_float4(0.f, 0.f, 0.f, 0.f);
            if (ns < n)
                vv = *(const float4*)(key + (size_t)samp_s[ns] * NI
                                          + ic * (NI / IC) + (e4 << 2));
            *(float4*)&key_s[ns][e4 << 2] = vv;
        }
        __syncthreads();

        float4 acc[NMAX];
        #pragma unroll
        for (int j = 0; j < NMAX; ++j) acc[j] = make_float4(0.f, 0.f, 0.f, 0.f);

        // rows per wave: il = w + 4*k, k = 0..31; UF=8 loads in flight
        #pragma unroll
        for (int k0 = 0; k0 < 32; k0 += UF) {
            float4 wv[UF];
            #pragma unroll
            for (int u = 0; u < UF; ++u)
                wv[u] = *(const float4*)(Wp + (size_t)(w + 4 * (k0 + u)) * NC + c4);
            #pragma unroll
            for (int u = 0; u < UF; ++u) {
                const int il = w + 4 * (k0 + u);
                #pragma unroll
                for (int j = 0; j < NMAX; ++j) {
                    const float k = key_s[j][il];
                    acc[j].x = fmaf(k, wv[u].x, acc[j].x);
                    acc[j].y = fmaf(k, wv[u].y, acc[j].y);
                    acc[j].z = fmaf(k, wv[u].z, acc[j].z);
                    acc[j].w = fmaf(k, wv[u].w, acc[j].w);
                }
            }
        }

        #pragma unroll
        for (int r = 0; r < 4; ++r) {     // cross-wave reduce, 2 samples/round
            __syncthreads();
            *(float4*)&red_s[w][0][c4] = acc[2 * r];
            *(float4*)&red_s[w][1][c4] = acc[2 * r + 1];
            __syncthreads();
            const float s0 = red_s[0][0][tid] + red_s[1][0][tid]
                           + red_s[2][0][tid] + red_s[3][0][tid];
            const float s1 = red_s[0][1][tid] + red_s[1][1][tid]
                           + red_s[2][1][tid] + red_s[3][1][tid];
            if (2 * r < n)
                partial[((size_t)ic * NB + samp_s[2 * r]) * NC + tid] = s0;
            if (2 * r + 1 < n)
                partial[((size_t)ic * NB + samp_s[2 * r + 1]) * NC + tid] = s1;
        }
    }
}

// ---------------- Kernel 3: reduce partials + bias, softmax, write prob -----
__global__ __launch_bounds__(256) void softmax_kernel(
        const int*   __restrict__ shard,
        const float* __restrict__ bias,
        const float* __restrict__ partial,
        float*       __restrict__ outq) {
    const int b    = blockIdx.x;
    const int tid  = threadIdx.x;
    const int wv   = tid >> 6;
    const int lane = tid & 63;

    float lg = bias[(size_t)shard[b] * NC + tid];
    #pragma unroll
    for (int ic = 0; ic < IC; ++ic)
        lg += partial[((size_t)ic * NB + b) * NC + tid];

    __shared__ float xw[4];
    float m = lg;
    #pragma unroll
    for (int off = 32; off >= 1; off >>= 1)
        m = fmaxf(m, __shfl_xor(m, off, 64));
    if (lane == 0) xw[wv] = m;
    __syncthreads();
    m = fmaxf(fmaxf(xw[0], xw[1]), fmaxf(xw[2], xw[3]));
    const float e = __expf(lg - m);
    float sm = e;
    #pragma unroll
    for (int off = 32; off >= 1; off >>= 1)
        sm += __shfl_xor(sm, off, 64);
    __syncthreads();
    if (lane == 0) xw[wv] = sm;
    __syncthreads();
    sm = xw[0] + xw[1] + xw[2] + xw[3];
    outq[(size_t)b * NC + tid] = e / sm;
}

// ---------------- Kernel 4: combine, block (shard, o-chunk) -----------------
// lat_h[b][oc*128 + o] = sum_c prob[b][c] * L[s][c][oc*128 + o]
__global__ __launch_bounds__(256) void combine_kernel(
        const int*   __restrict__ order,
        const int*   __restrict__ base,
        const int*   __restrict__ cnt,
        const float* __restrict__ prob,
        const float* __restrict__ lat,
        float*       __restrict__ outp) {
    const int s  = blockIdx.x >> 3;
    const int oc = blockIdx.x & 7;
    const int n_tot = cnt[s];
    if (n_tot == 0) return;
    const int b0  = base[s];
    const int tid = threadIdx.x;
    const int hw  = tid >> 5;            // half-wave = c-phase 0..7
    const int o4  = (tid & 31) << 2;     // 4 outputs per lane within 128-chunk

    const float* __restrict__ Lp = lat + (size_t)s * (NC * NO) + oc * (NO / OC);

    __shared__ float prob_s[NMAX][NC];       // 8 KB
    __shared__ float red_s[8][2][NO / OC];   // [8][2][128] 8 KB
    __shared__ int   samp_s[NMAX];

    for (int p0 = 0; p0 < n_tot; p0 += NMAX) {
        const int n = min(NMAX, n_tot - p0);
        __syncthreads();
        if (tid < n) samp_s[tid] = order[b0 + p0 + tid];
        __syncthreads();

        // stage prob: 8 samples x 256 floats = 512 float4 (2/thread)
        for (int idx = tid; idx < NMAX * 64; idx += 256) {
            const int ns = idx >> 6;
            const int e4 = idx & 63;
            float4 v = make_float4(0.f, 0.f, 0.f, 0.f);
            if (ns < n)
                v = *(const float4*)(prob + (size_t)samp_s[ns] * NC + (e4 << 2));
            *(float4*)&prob_s[ns][e4 << 2] = v;
        }
        __syncthreads();

        float4 acc[NMAX];
        #pragma unroll
        for (int j = 0; j < NMAX; ++j) acc[j] = make_float4(0.f, 0.f, 0.f, 0.f);

        // c = hw + 8*k, k = 0..31; UF=8 loads in flight
        #pragma unroll
        for (int k0 = 0; k0 < 32; k0 += UF) {
            float4 lv[UF];
            #pragma unroll
            for (int u = 0; u < UF; ++u)
                lv[u] = *(const float4*)(Lp + (size_t)(hw + 8 * (k0 + u)) * NO + o4);
            #pragma unroll
            for (int u = 0; u < UF; ++u) {
                const int c = hw + 8 * (k0 + u);
                #pragma unroll
                for (int j = 0; j < NMAX; ++j) {
                    const float p = prob_s[j][c];
                    acc[j].x = fmaf(p, lv[u].x, acc[j].x);
                    acc[j].y = fmaf(p, lv[u].y, acc[j].y);
                    acc[j].z = fmaf(p, lv[u].z, acc[j].z);
                    acc[j].w = fmaf(p, lv[u].w, acc[j].w);
                }
            }
        }

        // cross-phase reduce (8 phases), 2 samples per round
        #pragma unroll
        for (int r = 0; r < 4; ++r) {
            __syncthreads();
            *(float4*)&red_s[hw][0][o4] = acc[2 * r];
            *(float4*)&red_s[hw][1][o4] = acc[2 * r + 1];
            __syncthreads();
            const int sel = tid >> 7;            // 0/1 -> which sample
            const int o   = tid & 127;
            float sum = red_s[0][sel][o] + red_s[1][sel][o]
                      + red_s[2][sel][o] + red_s[3][sel][o]
                      + red_s[4][sel][o] + red_s[5][sel][o]
                      + red_s[6][sel][o] + red_s[7][sel][o];
            const int j = 2 * r + sel;
            if (j < n)
                outp[(size_t)samp_s[j] * NO + oc * (NO / OC) + o] = sum;
        }
    }
}

// ---------------- launch ----------------------------------------------------
extern "C" void kernel_launch(void* const* d_in, const int* in_sizes, int n_in,
                              void* d_out, int out_size, void* d_ws, size_t ws_size,
                              hipStream_t stream) {
    const int*   shard = (const int*)  d_in[0];
    const float* key   = (const float*)d_in[1];
    const float* lat   = (const float*)d_in[2];
    const float* wgt   = (const float*)d_in[3];
    const float* bias  = (const float*)d_in[4];

    float* outp = (float*)d_out;                       // lat_h [NB][NO]
    float* outq = (float*)d_out + (size_t)NB * NO;     // prob  [NB][NC]

    int*   order   = (int*)d_ws;           // [NB]
    int*   base    = order + NB;           // [NSH]
    int*   cnt     = base + NSH;           // [NSH]
    float* partial = (float*)(cnt + NSH);  // [IC][NB][NC] = 8 MB

    group_kernel  <<<1,        512, 0, stream>>>(shard, order, base, cnt);
    logit_kernel  <<<NSH * IC, 256, 0, stream>>>(order, base, cnt, key, wgt, partial);
    softmax_kernel<<<NB,       256, 0, stream>>>(shard, bias, partial, outq);
    combine_kernel<<<NSH * OC, 256, 0, stream>>>(order, base, cnt, outq, lat, outp);
}

// Round 6
// 197.284 us; speedup vs baseline: 5.3226x; 1.5089x over previous
//
#include <hip/hip_runtime.h>

#define NSH 512    // NUM_SHARDS
#define NC  256    // NUM_CLUSTERS
#define NI  1024   // INPUT_SIZE
#define NO  1024   // OUTPUT_SIZE
#define NB  1024   // BATCH
#define NMAX 8     // samples per pass per shard-block
#define IC  4      // i-chunks for logit kernel   (chunk = 256 rows)
#define OC  4      // o-chunks for combine kernel (chunk = 256 cols)
#define UF  8      // float4 loads in flight per thread (loop NOT unrolled)

// ---------------- Kernel 1: group samples by shard (counting sort) ----------
__global__ __launch_bounds__(512) void group_kernel(const int* __restrict__ shard,
                                                    int* __restrict__ order,
                                                    int* __restrict__ base,
                                                    int* __restrict__ cnt) {
    __shared__ int h[NSH];
    __shared__ int woff[8];
    __shared__ int cur[NSH];
    const int tid  = threadIdx.x;      // 512 threads == NSH
    const int lane = tid & 63;
    const int w8   = tid >> 6;
    h[tid] = 0;
    __syncthreads();
    for (int i = tid; i < NB; i += 512) atomicAdd(&h[shard[i]], 1);
    __syncthreads();
    const int v = h[tid];
    int inc = v;                        // inclusive scan within wave
    #pragma unroll
    for (int off = 1; off < 64; off <<= 1) {
        int t = __shfl_up(inc, off, 64);
        if (lane >= off) inc += t;
    }
    if (lane == 63) woff[w8] = inc;
    __syncthreads();
    if (tid == 0) {
        int a = 0;
        #pragma unroll
        for (int i = 0; i < 8; ++i) { int t = woff[i]; woff[i] = a; a += t; }
    }
    __syncthreads();
    const int b0 = woff[w8] + inc - v;  // exclusive prefix
    base[tid] = b0;
    cnt[tid]  = v;
    cur[tid]  = b0;
    __syncthreads();
    for (int i = tid; i < NB; i += 512) {
        int pos = atomicAdd(&cur[shard[i]], 1);
        order[pos] = i;
    }
}

// ---------------- Kernel 2: partial logits, block (shard, i-chunk) ----------
// partial[ic][b][c] = sum_{i in chunk} key[b][i] * W[s][i][c]
__global__ __launch_bounds__(256) void logit_kernel(
        const int*   __restrict__ order,
        const int*   __restrict__ base,
        const int*   __restrict__ cnt,
        const float* __restrict__ key,
        const float* __restrict__ wgt,
        float*       __restrict__ partial) {
    const int s  = blockIdx.x >> 2;
    const int ic = blockIdx.x & 3;
    const int n_tot = cnt[s];
    if (n_tot == 0) return;
    const int b0  = base[s];
    const int tid = threadIdx.x;
    const int w   = tid >> 6;            // i-phase (wave)
    const int c4  = (tid & 63) << 2;     // 4 clusters per lane

    const float* __restrict__ Wp =
        wgt + (size_t)s * (NI * NC) + (size_t)(ic * (NI / IC)) * NC;

    __shared__ float key_s[NMAX][NI / IC];  // [8][256]  8 KB
    __shared__ float red_s[4][2][NC];       //           8 KB
    __shared__ int   samp_s[NMAX];

    for (int p0 = 0; p0 < n_tot; p0 += NMAX) {
        const int n = min(NMAX, n_tot - p0);
        __syncthreads();
        if (tid < n) samp_s[tid] = order[b0 + p0 + tid];
        __syncthreads();

        // stage key chunk: 8 samples x 256 floats = 512 float4 (2/thread)
        for (int idx = tid; idx < NMAX * 64; idx += 256) {
            const int ns = idx >> 6;
            const int e4 = idx & 63;
            float4 vv = make_float4(0.f, 0.f, 0.f, 0.f);
            if (ns < n)
                vv = *(const float4*)(key + (size_t)samp_s[ns] * NI
                                          + ic * (NI / IC) + (e4 << 2));
            *(float4*)&key_s[ns][e4 << 2] = vv;
        }
        __syncthreads();

        float4 acc[NMAX];
        #pragma unroll
        for (int j = 0; j < NMAX; ++j) acc[j] = make_float4(0.f, 0.f, 0.f, 0.f);

        // rows per wave: il = w + 4*k, k = 0..63; UF loads in flight.
        // NOTE: outer loop deliberately NOT unrolled (keeps VGPR ~100,
        // occupancy 4-5 waves/SIMD — R5's full unroll at 188 VGPR regressed).
        for (int k0 = 0; k0 < 64; k0 += UF) {
            float4 wv[UF];
            #pragma unroll
            for (int u = 0; u < UF; ++u)
                wv[u] = *(const float4*)(Wp + (size_t)(w + 4 * (k0 + u)) * NC + c4);
            #pragma unroll
            for (int u = 0; u < UF; ++u) {
                const int il = w + 4 * (k0 + u);
                #pragma unroll
                for (int j = 0; j < NMAX; ++j) {
                    const float k = key_s[j][il];
                    acc[j].x = fmaf(k, wv[u].x, acc[j].x);
                    acc[j].y = fmaf(k, wv[u].y, acc[j].y);
                    acc[j].z = fmaf(k, wv[u].z, acc[j].z);
                    acc[j].w = fmaf(k, wv[u].w, acc[j].w);
                }
            }
        }

        #pragma unroll
        for (int r = 0; r < 4; ++r) {     // cross-wave reduce, 2 samples/round
            __syncthreads();
            *(float4*)&red_s[w][0][c4] = acc[2 * r];
            *(float4*)&red_s[w][1][c4] = acc[2 * r + 1];
            __syncthreads();
            const float s0 = red_s[0][0][tid] + red_s[1][0][tid]
                           + red_s[2][0][tid] + red_s[3][0][tid];
            const float s1 = red_s[0][1][tid] + red_s[1][1][tid]
                           + red_s[2][1][tid] + red_s[3][1][tid];
            if (2 * r < n)
                partial[((size_t)ic * NB + samp_s[2 * r]) * NC + tid] = s0;
            if (2 * r + 1 < n)
                partial[((size_t)ic * NB + samp_s[2 * r + 1]) * NC + tid] = s1;
        }
    }
}

// ---------------- Kernel 3: fused softmax + combine, block (shard, o-chunk) -
// logits from partial[] (visible: kernel boundary = full barrier+flush),
// block-local batched softmax, oc==0 writes prob, then stream L panel.
__global__ __launch_bounds__(256) void combine_kernel(
        const int*   __restrict__ order,
        const int*   __restrict__ base,
        const int*   __restrict__ cnt,
        const float* __restrict__ partial,
        const float* __restrict__ bias,
        const float* __restrict__ lat,
        float*       __restrict__ outq,
        float*       __restrict__ outp) {
    const int s  = blockIdx.x >> 2;
    const int oc = blockIdx.x & 3;
    const int n_tot = cnt[s];
    if (n_tot == 0) return;
    const int b0   = base[s];
    const int tid  = threadIdx.x;
    const int w    = tid >> 6;           // wave = c-phase 0..3
    const int lane = tid & 63;
    const int o4   = lane << 2;          // 4 outputs per lane within 256-chunk

    const float* __restrict__ Lp = lat + (size_t)s * (NC * NO) + oc * (NO / OC);
    const float  bsc = bias[(size_t)s * NC + tid];   // bias for cluster c = tid

    __shared__ float prob_s[NMAX][NC];       // 8 KB
    __shared__ float red_s[4][2][NO / OC];   // [4][2][256] 8 KB
    __shared__ float xm[4][NMAX];
    __shared__ float xs[4][NMAX];
    __shared__ int   samp_s[NMAX];

    for (int p0 = 0; p0 < n_tot; p0 += NMAX) {
        const int n = min(NMAX, n_tot - p0);
        __syncthreads();
        if (tid < n) samp_s[tid] = order[b0 + p0 + tid];
        __syncthreads();

        // ---- logits: thread tid owns cluster c = tid, for n samples ----
        float lg[NMAX];
        #pragma unroll
        for (int j = 0; j < NMAX; ++j) {
            lg[j] = -1e30f;
            if (j < n) {
                const int b = samp_s[j];
                float v = bsc;
                #pragma unroll
                for (int ic = 0; ic < IC; ++ic)
                    v += partial[((size_t)ic * NB + b) * NC + tid];
                lg[j] = v;
            }
        }
        // ---- batched block softmax over 256 clusters ----
        float m[NMAX], e[NMAX];
        #pragma unroll
        for (int j = 0; j < NMAX; ++j) {
            m[j] = lg[j];
            #pragma unroll
            for (int off = 32; off >= 1; off >>= 1)
                m[j] = fmaxf(m[j], __shfl_xor(m[j], off, 64));
        }
        if (lane == 0) {
            #pragma unroll
            for (int j = 0; j < NMAX; ++j) xm[w][j] = m[j];
        }
        __syncthreads();
        #pragma unroll
        for (int j = 0; j < NMAX; ++j) {
            const float mm = fmaxf(fmaxf(xm[0][j], xm[1][j]),
                                   fmaxf(xm[2][j], xm[3][j]));
            e[j] = __expf(lg[j] - mm);
            float sm = e[j];
            #pragma unroll
            for (int off = 32; off >= 1; off >>= 1)
                sm += __shfl_xor(sm, off, 64);
            if (lane == 0) xs[w][j] = sm;
        }
        __syncthreads();
        #pragma unroll
        for (int j = 0; j < NMAX; ++j) {
            const float S = xs[0][j] + xs[1][j] + xs[2][j] + xs[3][j];
            const float p = e[j] / S;
            prob_s[j][tid] = p;                       // finite even for j >= n
            if (oc == 0 && j < n)
                outq[(size_t)samp_s[j] * NC + tid] = p;
        }
        __syncthreads();

        // ---- stream L panel: c = w + 4*k, k = 0..63; UF loads in flight ----
        float4 acc[NMAX];
        #pragma unroll
        for (int j = 0; j < NMAX; ++j) acc[j] = make_float4(0.f, 0.f, 0.f, 0.f);

        for (int k0 = 0; k0 < 64; k0 += UF) {         // NOT unrolled (VGPR)
            float4 lv[UF];
            #pragma unroll
            for (int u = 0; u < UF; ++u)
                lv[u] = *(const float4*)(Lp + (size_t)(w + 4 * (k0 + u)) * NO + o4);
            #pragma unroll
            for (int u = 0; u < UF; ++u) {
                const int c = w + 4 * (k0 + u);
                #pragma unroll
                for (int j = 0; j < NMAX; ++j) {
                    const float p = prob_s[j][c];
                    acc[j].x = fmaf(p, lv[u].x, acc[j].x);
                    acc[j].y = fmaf(p, lv[u].y, acc[j].y);
                    acc[j].z = fmaf(p, lv[u].z, acc[j].z);
                    acc[j].w = fmaf(p, lv[u].w, acc[j].w);
                }
            }
        }

        // cross-wave reduce (4 phases), 2 samples per round
        #pragma unroll
        for (int r = 0; r < 4; ++r) {
            __syncthreads();
            *(float4*)&red_s[w][0][o4] = acc[2 * r];
            *(float4*)&red_s[w][1][o4] = acc[2 * r + 1];
            __syncthreads();
            const float s0 = red_s[0][0][tid] + red_s[1][0][tid]
                           + red_s[2][0][tid] + red_s[3][0][tid];
            const float s1 = red_s[0][1][tid] + red_s[1][1][tid]
                           + red_s[2][1][tid] + red_s[3][1][tid];
            if (2 * r < n)
                outp[(size_t)samp_s[2 * r] * NO + oc * (NO / OC) + tid] = s0;
            if (2 * r + 1 < n)
                outp[(size_t)samp_s[2 * r + 1] * NO + oc * (NO / OC) + tid] = s1;
        }
    }
}

// ---------------- launch ----------------------------------------------------
extern "C" void kernel_launch(void* const* d_in, const int* in_sizes, int n_in,
                              void* d_out, int out_size, void* d_ws, size_t ws_size,
                              hipStream_t stream) {
    const int*   shard = (const int*)  d_in[0];
    const float* key   = (const float*)d_in[1];
    const float* lat   = (const float*)d_in[2];
    const float* wgt   = (const float*)d_in[3];
    const float* bias  = (const float*)d_in[4];

    float* outp = (float*)d_out;                       // lat_h [NB][NO]
    float* outq = (float*)d_out + (size_t)NB * NO;     // prob  [NB][NC]

    int*   order   = (int*)d_ws;           // [NB]
    int*   base    = order + NB;           // [NSH]
    int*   cnt     = base + NSH;           // [NSH]
    float* partial = (float*)(cnt + NSH);  // [IC][NB][NC] = 4 MB

    group_kernel  <<<1,        512, 0, stream>>>(shard, order, base, cnt);
    logit_kernel  <<<NSH * IC, 256, 0, stream>>>(order, base, cnt, key, wgt, partial);
    combine_kernel<<<NSH * OC, 256, 0, stream>>>(order, base, cnt, partial, bias,
                                                 lat, outq, outp);
}